// Round 2
// baseline (1576.621 us; speedup 1.0000x reference)
//
#include <hip/hip_runtime.h>
#include <stdint.h>

typedef __attribute__((ext_vector_type(8))) short short8;
typedef __attribute__((ext_vector_type(4))) float f32x4;

#define D_MODEL 4096
#define N_HEADS 32
#define HEAD_DIM 128
#define S_LEN 2048
#define BSEQ 4096          /* B*S */
#define QKV_N 12288
#define SCALE 0.08838834764831843f  /* 1/sqrt(128) */

__device__ __forceinline__ float bf2f(unsigned short u) {
    union { unsigned int i; float f; } c; c.i = ((unsigned int)u) << 16; return c.f;
}
__device__ __forceinline__ unsigned short f2bf(float f) {
    union { float f; unsigned int i; } c; c.f = f;
    unsigned int r = c.i + 0x7FFFu + ((c.i >> 16) & 1u);   /* RNE, no NaN inputs */
    return (unsigned short)(r >> 16);
}

/* ---------------- fp32 -> bf16 convert ---------------- */
__global__ __launch_bounds__(256) void cvt_kernel(const float* __restrict__ in,
                                                  unsigned short* __restrict__ out, long n) {
    long i = ((long)blockIdx.x * blockDim.x + threadIdx.x) * 4;
    long stride = (long)gridDim.x * blockDim.x * 4;
    for (long p = i; p < n; p += stride) {
        float4 v = *reinterpret_cast<const float4*>(in + p);
        unsigned short o0 = f2bf(v.x), o1 = f2bf(v.y), o2 = f2bf(v.z), o3 = f2bf(v.w);
        unsigned long long pack = (unsigned long long)o0 | ((unsigned long long)o1 << 16)
                                | ((unsigned long long)o2 << 32) | ((unsigned long long)o3 << 48);
        *reinterpret_cast<unsigned long long*>(out + p) = pack;
    }
}

/* ---------------- GEMM  C[M][N] = A[M][K] * B[N][K]^T  (m97 structure) ----------------
   EPI 0: clip to +-8, store bf16.  EPI 1: store fp32. */
template<int EPI>
__global__ __launch_bounds__(256) void gemm_bt(const unsigned short* __restrict__ A,
                                               const unsigned short* __restrict__ B,
                                               void* __restrict__ Cout,
                                               int M, int N, int K) {
    __shared__ unsigned short As[128 * 32];
    __shared__ unsigned short Bs[128 * 32];
    const int tid = threadIdx.x;
    const int lane = tid & 63;
    const int wv = tid >> 6;
    const int wm = wv >> 1, wn = wv & 1;
    const int l15 = lane & 15, lg = lane >> 4;
    const int tm = blockIdx.y, tn = blockIdx.x;

    f32x4 acc[4][4] = {};

    for (int k0 = 0; k0 < K; k0 += 32) {
        __syncthreads();
#pragma unroll
        for (int i = 0; i < 2; ++i) {
            int r  = i * 64 + (tid >> 2);
            int kg = tid & 3;
            const unsigned short* srcA = A + (size_t)(tm * 128 + r) * K + k0 + kg * 8;
            const unsigned short* srcB = B + (size_t)(tn * 128 + r) * K + k0 + kg * 8;
            unsigned short* dstA = As + (size_t)(i * 256 + (tid & 192)) * 8;
            unsigned short* dstB = Bs + (size_t)(i * 256 + (tid & 192)) * 8;
            __builtin_amdgcn_global_load_lds((const __attribute__((address_space(1))) void*)srcA,
                                             (__attribute__((address_space(3))) void*)dstA, 16, 0, 0);
            __builtin_amdgcn_global_load_lds((const __attribute__((address_space(1))) void*)srcB,
                                             (__attribute__((address_space(3))) void*)dstB, 16, 0, 0);
        }
        __syncthreads();
        short8 af[4], bf[4];
#pragma unroll
        for (int m = 0; m < 4; ++m)
            af[m] = *reinterpret_cast<const short8*>(As + (wm * 64 + m * 16 + l15) * 32 + lg * 8);
#pragma unroll
        for (int n = 0; n < 4; ++n)
            bf[n] = *reinterpret_cast<const short8*>(Bs + (wn * 64 + n * 16 + l15) * 32 + lg * 8);
#pragma unroll
        for (int m = 0; m < 4; ++m)
#pragma unroll
            for (int n = 0; n < 4; ++n)
                acc[m][n] = __builtin_amdgcn_mfma_f32_16x16x32_bf16(af[m], bf[n], acc[m][n], 0, 0, 0);
    }

#pragma unroll
    for (int m = 0; m < 4; ++m) {
#pragma unroll
        for (int n = 0; n < 4; ++n) {
            int gn = tn * 128 + wn * 64 + n * 16 + l15;
#pragma unroll
            for (int j = 0; j < 4; ++j) {
                int gm = tm * 128 + wm * 64 + m * 16 + lg * 4 + j;
                float v = acc[m][n][j];
                if (EPI == 0) {
                    v = fminf(fmaxf(v, -8.0f), 8.0f);
                    ((unsigned short*)Cout)[(size_t)gm * N + gn] = f2bf(v);
                } else {
                    ((float*)Cout)[(size_t)gm * N + gn] = v;
                }
            }
        }
    }
}

/* ---------------- LayerNorm over d_model for q,k slices (in place, bf16) ---------------- */
__global__ __launch_bounds__(256) void qk_ln(unsigned short* __restrict__ qkv,
                                             const float* __restrict__ qw, const float* __restrict__ qb,
                                             const float* __restrict__ kw, const float* __restrict__ kb) {
    int row = blockIdx.x;           /* 0..8191 : 4096 q-rows then 4096 k-rows */
    int isk = row >> 12;
    int m   = row & 4095;
    unsigned short* p = qkv + (size_t)m * QKV_N + isk * D_MODEL;
    const float* w  = isk ? kw : qw;
    const float* bb = isk ? kb : qb;
    int tid = threadIdx.x;

    short8 v0 = *reinterpret_cast<const short8*>(p + tid * 16);
    short8 v1 = *reinterpret_cast<const short8*>(p + tid * 16 + 8);
    float x[16];
    float s = 0.f, s2 = 0.f;
#pragma unroll
    for (int i = 0; i < 8; ++i) {
        x[i]     = bf2f((unsigned short)v0[i]);
        x[8 + i] = bf2f((unsigned short)v1[i]);
    }
#pragma unroll
    for (int i = 0; i < 16; ++i) { s += x[i]; s2 += x[i] * x[i]; }

#pragma unroll
    for (int d = 1; d < 64; d <<= 1) { s += __shfl_xor(s, d, 64); s2 += __shfl_xor(s2, d, 64); }
    __shared__ float red[8];
    int wvv = tid >> 6, lane = tid & 63;
    if (lane == 0) { red[wvv] = s; red[4 + wvv] = s2; }
    __syncthreads();
    s  = red[0] + red[1] + red[2] + red[3];
    s2 = red[4] + red[5] + red[6] + red[7];
    float mu  = s * (1.0f / 4096.0f);
    float var = s2 * (1.0f / 4096.0f) - mu * mu;
    float rs  = rsqrtf(var + 1e-5f);

    unsigned short y[16];
#pragma unroll
    for (int i = 0; i < 16; ++i) {
        int c = tid * 16 + i;
        y[i] = f2bf((x[i] - mu) * rs * w[c] + bb[c]);
    }
    unsigned long long pk[4];
#pragma unroll
    for (int q = 0; q < 4; ++q)
        pk[q] = (unsigned long long)y[q*4] | ((unsigned long long)y[q*4+1] << 16)
              | ((unsigned long long)y[q*4+2] << 32) | ((unsigned long long)y[q*4+3] << 48);
    *reinterpret_cast<unsigned long long*>(p + tid * 16)      = pk[0];
    *reinterpret_cast<unsigned long long*>(p + tid * 16 + 4)  = pk[1];
    *reinterpret_cast<unsigned long long*>(p + tid * 16 + 8)  = pk[2];
    *reinterpret_cast<unsigned long long*>(p + tid * 16 + 12) = pk[3];
}

/* ---------------- Flash attention, causal + ALiBi ----------------
   grid: x = S/64 q-tiles, y = B*H.  256 thr = 4 waves x 16 q-rows. */
__global__ __launch_bounds__(256) void attn_kernel(const unsigned short* __restrict__ qkv,
                                                   unsigned short* __restrict__ attn_out) {
    __shared__ unsigned short Klds[64 * 128];   /* swizzled: byte = r*256 + (c ^ ((r&7)<<4)) */
    __shared__ unsigned short Vt[128 * 64];     /* swizzled: byte = d*128 + (c ^ (((d^(d>>3))&7)<<4)) */
    __shared__ unsigned short Plds[4][16 * 64]; /* per-wave, byte = row*128 + (c ^ ((row&7)<<4)) */

    const int q0 = blockIdx.x * 64;
    const int bh = blockIdx.y;
    const int bb = bh >> 5, h = bh & 31;
    const int tid = threadIdx.x;
    const int lane = tid & 63, wv = tid >> 6;
    const int l15 = lane & 15, lg = lane >> 4;

    /* Q fragments, straight from global (post-LN bf16) */
    const int qrow_g = bb * S_LEN + q0 + wv * 16 + l15;
    const unsigned short* qbase = qkv + (size_t)qrow_g * QKV_N + h * HEAD_DIM;
    short8 qf[4];
#pragma unroll
    for (int kc = 0; kc < 4; ++kc)
        qf[kc] = *reinterpret_cast<const short8*>(qbase + kc * 32 + lg * 8);

    f32x4 o[8] = {};
    float mrun[4] = {-1e30f, -1e30f, -1e30f, -1e30f};
    float lrun[4] = {0.f, 0.f, 0.f, 0.f};
    const float slope = exp2f(-0.25f * (float)(h + 1));

    for (int kv0 = 0; kv0 <= q0; kv0 += 64) {
        __syncthreads();
        /* stage K tile + transposed V tile */
#pragma unroll
        for (int i = 0; i < 4; ++i) {
            int u = i * 256 + tid;           /* 0..1023 */
            int r = u >> 4, dg = u & 15;
            const unsigned short* base = qkv + (size_t)(bb * S_LEN + kv0 + r) * QKV_N
                                       + D_MODEL + h * HEAD_DIM + dg * 8;
            short8 kx = *reinterpret_cast<const short8*>(base);
            short8 vx = *reinterpret_cast<const short8*>(base + D_MODEL);
            *reinterpret_cast<short8*>((char*)Klds + r * 256 + ((dg * 16) ^ ((r & 7) << 4))) = kx;
#pragma unroll
            for (int ii = 0; ii < 8; ++ii) {
                int d = dg * 8 + ii;
                *reinterpret_cast<unsigned short*>((char*)Vt + d * 128 +
                    ((r * 2) ^ (((d ^ (d >> 3)) & 7) << 4))) = (unsigned short)vx[ii];
            }
        }
        __syncthreads();

        /* S = Q K^T */
        f32x4 sacc[4] = {};
#pragma unroll
        for (int n16 = 0; n16 < 4; ++n16) {
            int rr = n16 * 16 + l15;
#pragma unroll
            for (int kc = 0; kc < 4; ++kc) {
                short8 kf = *reinterpret_cast<const short8*>((char*)Klds + rr * 256 +
                               ((kc * 64 + lg * 16) ^ ((rr & 7) << 4)));
                sacc[n16] = __builtin_amdgcn_mfma_f32_16x16x32_bf16(qf[kc], kf, sacc[n16], 0, 0, 0);
            }
        }

        /* scale + alibi + causal mask, tile row-max */
        float pmax[4] = {-1e30f, -1e30f, -1e30f, -1e30f};
#pragma unroll
        for (int n16 = 0; n16 < 4; ++n16) {
            int kvi = kv0 + n16 * 16 + l15;
#pragma unroll
            for (int j = 0; j < 4; ++j) {
                int qi = q0 + wv * 16 + lg * 4 + j;
                float sc = sacc[n16][j] * SCALE + slope * (float)(kvi - qi);
                sc = (kvi <= qi) ? sc : -1e30f;
                sacc[n16][j] = sc;
                pmax[j] = fmaxf(pmax[j], sc);
            }
        }
#pragma unroll
        for (int j = 0; j < 4; ++j) {
#pragma unroll
            for (int d = 1; d < 16; d <<= 1)
                pmax[j] = fmaxf(pmax[j], __shfl_xor(pmax[j], d, 64));
            float mn = fmaxf(mrun[j], pmax[j]);
            float al = expf(mrun[j] - mn);
            mrun[j] = mn;
            lrun[j] *= al;
#pragma unroll
            for (int d16 = 0; d16 < 8; ++d16) o[d16][j] *= al;
        }
        float lsum[4] = {0.f, 0.f, 0.f, 0.f};
#pragma unroll
        for (int n16 = 0; n16 < 4; ++n16)
#pragma unroll
            for (int j = 0; j < 4; ++j) {
                float pv = expf(sacc[n16][j] - mrun[j]);
                sacc[n16][j] = pv;
                lsum[j] += pv;
            }
#pragma unroll
        for (int j = 0; j < 4; ++j) {
#pragma unroll
            for (int d = 1; d < 16; d <<= 1)
                lsum[j] += __shfl_xor(lsum[j], d, 64);
            lrun[j] += lsum[j];
        }

        /* P -> per-wave LDS (bf16) in A-fragment-readable layout */
#pragma unroll
        for (int n16 = 0; n16 < 4; ++n16)
#pragma unroll
            for (int j = 0; j < 4; ++j) {
                int prow = lg * 4 + j;
                int pcol = n16 * 16 + l15;
                *reinterpret_cast<unsigned short*>((char*)Plds[wv] + prow * 128 +
                    ((pcol * 2) ^ ((prow & 7) << 4))) = f2bf(sacc[n16][j]);
            }

        /* O += P V */
#pragma unroll
        for (int kc2 = 0; kc2 < 2; ++kc2) {
            short8 pf = *reinterpret_cast<const short8*>((char*)Plds[wv] + l15 * 128 +
                           ((kc2 * 64 + lg * 16) ^ ((l15 & 7) << 4)));
#pragma unroll
            for (int d16 = 0; d16 < 8; ++d16) {
                int d = d16 * 16 + l15;
                short8 vf = *reinterpret_cast<const short8*>((char*)Vt + d * 128 +
                               ((kc2 * 64 + lg * 16) ^ (((d ^ (d >> 3)) & 7) << 4)));
                o[d16] = __builtin_amdgcn_mfma_f32_16x16x32_bf16(pf, vf, o[d16], 0, 0, 0);
            }
        }
    }

    float inv[4];
#pragma unroll
    for (int j = 0; j < 4; ++j) inv[j] = 1.0f / lrun[j];
#pragma unroll
    for (int d16 = 0; d16 < 8; ++d16)
#pragma unroll
        for (int j = 0; j < 4; ++j) {
            int qi = q0 + wv * 16 + lg * 4 + j;
            attn_out[(size_t)(bb * S_LEN + qi) * D_MODEL + h * HEAD_DIM + d16 * 16 + l15] =
                f2bf(o[d16][j] * inv[j]);
        }
}

extern "C" void kernel_launch(void* const* d_in, const int* in_sizes, int n_in,
                              void* d_out, int out_size, void* d_ws, size_t ws_size,
                              hipStream_t stream) {
    const float* hidden = (const float*)d_in[0];
    const float* w_qkv  = (const float*)d_in[1];
    const float* q_ln_w = (const float*)d_in[2];
    const float* q_ln_b = (const float*)d_in[3];
    const float* k_ln_w = (const float*)d_in[4];
    const float* k_ln_b = (const float*)d_in[5];
    const float* w_out  = (const float*)d_in[6];
    float* out = (float*)d_out;

    char* ws = (char*)d_ws;
    unsigned short* h_bf    = (unsigned short*)(ws);                    /* 33.5 MB  */
    unsigned short* wqkv_bf = (unsigned short*)(ws + 33554432ULL);      /* 100.7 MB */
    unsigned short* wout_bf = (unsigned short*)(ws + 134217728ULL);     /* 33.5 MB  */
    unsigned short* qkv_bf  = (unsigned short*)(ws + 167772160ULL);     /* 100.7 MB */
    unsigned short* attn_bf = h_bf;   /* reuse: h consumed by QKV GEMM before attention writes */

    cvt_kernel<<<2048, 256, 0, stream>>>(hidden, h_bf,    (long)BSEQ * D_MODEL);
    cvt_kernel<<<2048, 256, 0, stream>>>(w_qkv,  wqkv_bf, (long)QKV_N * D_MODEL);
    cvt_kernel<<<2048, 256, 0, stream>>>(w_out,  wout_bf, (long)D_MODEL * D_MODEL);

    gemm_bt<0><<<dim3(QKV_N / 128, BSEQ / 128), 256, 0, stream>>>(h_bf, wqkv_bf, qkv_bf,
                                                                  BSEQ, QKV_N, D_MODEL);
    qk_ln<<<8192, 256, 0, stream>>>(qkv_bf, q_ln_w, q_ln_b, k_ln_w, k_ln_b);
    attn_kernel<<<dim3(S_LEN / 64, 64), 256, 0, stream>>>(qkv_bf, attn_bf);
    gemm_bt<1><<<dim3(D_MODEL / 128, BSEQ / 128), 256, 0, stream>>>(attn_bf, wout_bf, out,
                                                                    BSEQ, D_MODEL, D_MODEL);
}